// Round 1
// baseline (364.711 us; speedup 1.0000x reference)
//
#include <hip/hip_runtime.h>

#define NB 32      // B
#define LL 256     // L
#define LQn 128    // LQ
#define Dv 41
#define Cc 82
#define CP 84      // padded channel count
#define ET 128
#define NH 128
#define TNH 384

// workspace layout (float units)
#define OFF_QALL 0
#define OFF_KALL (OFF_QALL + NB*LQn*ET)        // q_all: 524288
#define OFF_XPAD (OFF_KALL + NB*LL*ET)         // k_all: 1048576
#define OFF_WCT  (OFF_XPAD + NB*LL*CP)         // x_pad: 688128
#define OFF_WHH2 (OFF_WCT + CP*768)            // WcT: 64512
#define OFF_ATT  (OFF_WHH2 + 2*64*TNH)         // whh2T (half2-as-int): 49152
#define OFF_XF   (OFF_ATT + NB*LQn*CP)         // att: 344064
#define OFF_XB   (OFF_XF + NB*LQn*TNH)
#define OFF_HCAT (OFF_XB + NB*LQn*TNH)
#define OFF_WQT  (OFF_HCAT + NB*LQn*2*NH)
#define OFF_WKT  (OFF_WQT + ET*ET)

typedef _Float16 h2_t __attribute__((ext_vector_type(2)));

__device__ __forceinline__ float quad_xor1_add(float x) {
  int y = __builtin_amdgcn_mov_dpp(__float_as_int(x), 0xB1, 0xF, 0xF, true);
  return x + __int_as_float(y);
}
__device__ __forceinline__ float quad_xor2_add(float x) {
  int y = __builtin_amdgcn_mov_dpp(__float_as_int(x), 0x4E, 0xF, 0xF, true);
  return x + __int_as_float(y);
}

// ---------------- K0: preprocessing ----------------
// a) pad x -> [B][L][84]; b) WcT[c][j] = (w_ih @ [Wo | bo])^T fused matrix (row82=bias,row83=0)
// c) whh2T[dir][k2][j] fp16-packed transposed Whh; d) WqT/WkT transposes
__global__ __launch_bounds__(256) void k0_prep(
    const float* __restrict__ x, const float* __restrict__ Wq,
    const float* __restrict__ Wk, const float* __restrict__ Wo,
    const float* __restrict__ bo,
    const float* __restrict__ wihf, const float* __restrict__ bihf,
    const float* __restrict__ wihb, const float* __restrict__ bihb,
    const float* __restrict__ whhf, const float* __restrict__ whhb,
    float* ws) {
  int bid = blockIdx.x;
  int t = threadIdx.x;
  if (bid < 2688) {                       // x_pad: 32*256*84 = 688128
    int idx = bid*256 + t;
    int c = idx % CP; int row = idx / CP;
    float v = (c < Cc) ? x[row*Cc + c] : 0.f;
    ws[OFF_XPAD + idx] = v;
  } else if (bid < 2940) {                // WcT: 768*84 = 64512
    int idx = (bid-2688)*256 + t;
    int c = idx % CP; int j = idx / CP;
    const float* wih = (j < TNH) ? wihf : wihb;
    const float* bih = (j < TNH) ? bihf : bihb;
    int jj = (j < TNH) ? j : j - TNH;
    float acc = 0.f;
    if (c < Cc) {
      for (int k = 0; k < NH; k++) acc = fmaf(wih[jj*NH+k], Wo[k*Cc + c], acc);
    } else if (c == Cc) {
      for (int k = 0; k < NH; k++) acc = fmaf(wih[jj*NH+k], bo[k], acc);
      acc += bih[jj];
    }
    ws[OFF_WCT + c*768 + j] = acc;
  } else if (bid < 3132) {                // whh2T: 2*64*384 = 49152
    int idx = (bid-2940)*256 + t;
    int j = idx % TNH; int k2 = (idx / TNH) & 63; int dir = idx / (64*TNH);
    const float* whh = dir ? whhb : whhf;
    float a = whh[j*NH + 2*k2];
    float b = whh[j*NH + 2*k2 + 1];
    union { _Float16 h[2]; unsigned int u; } pk;
    pk.h[0] = (_Float16)a; pk.h[1] = (_Float16)b;
    ((unsigned int*)ws)[OFF_WHH2 + idx] = pk.u;
  } else {                                // WqT/WkT: 2*16384
    int idx = (bid-3132)*256 + t;
    int j = idx & 127; int k = (idx >> 7) & 127; int w = idx >> 14;
    const float* W = w ? Wk : Wq;
    ws[(w ? OFF_WKT : OFF_WQT) + k*ET + j] = W[j*ET + k];
  }
}

// ---------------- K1: time-embed + projection ----------------
// 192 blocks x 256 thr; block = 64 rows. blocks 0..63: query rows (4096), 64..191: key rows (8192)
__global__ __launch_bounds__(256) void k1_embed_proj(
    const float* __restrict__ query, const float* __restrict__ tsteps,
    const float* __restrict__ bq, const float* __restrict__ bk,
    float* ws) {
  __shared__ float emb[64*132];
  __shared__ float wt[64*132];
  int bid = blockIdx.x, t = threadIdx.x;
  bool isQ = bid < 64;
  int rowbase = isQ ? bid*64 : (bid-64)*64;   // global flat row within section

  // embeds: 64 rows x 64 (sin,cos) pairs
  for (int ii = 0; ii < 16; ii++) {
    int p = t + ii*256;
    int r = p >> 6, i = p & 63;
    int grow = rowbase + r;
    float pos = isQ ? query[grow] : tsteps[grow];
    float dv = __expf(-(float)(2*i) * (2.302585092994046f/128.f));
    float ang = 48.f * pos * dv;
    float sv, cv; sincosf(ang, &sv, &cv);
    emb[r*132 + 2*i]     = sv;
    emb[r*132 + 2*i + 1] = cv;
  }

  const float* wtg  = ws + (isQ ? OFF_WQT : OFF_WKT);
  const float* bias = isQ ? bq : bk;
  int cq = t & 31, rh = t >> 5;               // j4 = cq*4 ; rows rh*8..rh*8+7
  float acc[8][4];
  for (int ri = 0; ri < 8; ri++)
    for (int u = 0; u < 4; u++) acc[ri][u] = bias[cq*4 + u];

  for (int kk = 0; kk < 128; kk += 64) {
    __syncthreads();
    // stage WT chunk [64][132]
    for (int ii = 0; ii < 32; ii++) {
      int idx = t + ii*256;
      int kl = idx >> 7, j = idx & 127;
      wt[kl*132 + j] = wtg[(kk+kl)*ET + j];
    }
    __syncthreads();
    for (int k4 = 0; k4 < 16; k4++) {
      float wv[4][4];
      #pragma unroll
      for (int u = 0; u < 4; u++) {
        float4 w4 = *(const float4*)&wt[(k4*4+u)*132 + cq*4];
        wv[u][0]=w4.x; wv[u][1]=w4.y; wv[u][2]=w4.z; wv[u][3]=w4.w;
      }
      #pragma unroll
      for (int ri = 0; ri < 8; ri++) {
        float4 e4 = *(const float4*)&emb[(rh*8+ri)*132 + kk + k4*4];
        float ev[4] = {e4.x, e4.y, e4.z, e4.w};
        #pragma unroll
        for (int u = 0; u < 4; u++)
          #pragma unroll
          for (int jj = 0; jj < 4; jj++)
            acc[ri][jj] = fmaf(ev[u], wv[u][jj], acc[ri][jj]);
      }
    }
  }
  int secbase = isQ ? OFF_QALL : OFF_KALL;
  for (int ri = 0; ri < 8; ri++) {
    int grow = rowbase + rh*8 + ri;
    float4 o4 = {acc[ri][0], acc[ri][1], acc[ri][2], acc[ri][3]};
    *(float4*)&ws[secbase + grow*ET + cq*4] = o4;
  }
}

// ---------------- K2: attention (scores -> e -> S -> att) ----------------
// 256 blocks (b x 8 q-tiles of 16 rows), 256 thr
__global__ __launch_bounds__(256) void k2_attn(float* ws) {
  __shared__ float sS[16*CP];     // S, then att (col82=1 bias aug, col83=0)
  __shared__ float se[16*260];    // scores, then e
  int bb = blockIdx.x >> 3, qt = blockIdx.x & 7;
  int t = threadIdx.x;
  int lane = t & 63, wv_ = t >> 6;
  int r4 = lane >> 2, seg = lane & 3;

  // q fragment in registers: row (qt*16+r4), k-range seg*32..+31
  float4 qreg[8];
  const float* qrow = ws + OFF_QALL + (bb*LQn + qt*16 + r4)*ET + seg*32;
  #pragma unroll
  for (int u = 0; u < 8; u++) qreg[u] = *(const float4*)&qrow[u*4];

  // phase 2: scores; wave w handles l in [w*64, w*64+64)
  const float* kb = ws + OFF_KALL + bb*LL*ET;
  for (int l = wv_*64; l < wv_*64 + 64; l++) {
    const float* krow = kb + l*ET + seg*32;
    float a0=0.f, a1=0.f, a2=0.f, a3=0.f;
    #pragma unroll
    for (int u = 0; u < 8; u++) {
      float4 kv = *(const float4*)&krow[u*4];
      float* aa = (u&3)==0 ? &a0 : (u&3)==1 ? &a1 : (u&3)==2 ? &a2 : &a3;
      *aa = fmaf(qreg[u].x, kv.x, *aa);
      *aa = fmaf(qreg[u].y, kv.y, *aa);
      *aa = fmaf(qreg[u].z, kv.z, *aa);
      *aa = fmaf(qreg[u].w, kv.w, *aa);
    }
    float a = (a0+a1) + (a2+a3);
    a = quad_xor1_add(a);
    a = quad_xor2_add(a);
    if (seg == 0) se[r4*260 + l] = a;
  }
  __syncthreads();

  // phase 3: row max + exp (scale folded in)
  {
    int rr = t >> 4, j0 = t & 15;
    float m = -1e30f;
    for (int i = 0; i < 16; i++) m = fmaxf(m, se[rr*260 + j0 + 16*i]);
    for (int msk = 1; msk < 16; msk <<= 1) m = fmaxf(m, __shfl_xor(m, msk));
    for (int i = 0; i < 16; i++) {
      int c0 = j0 + 16*i;
      se[rr*260 + c0] = __expf((se[rr*260 + c0] - m) * 0.08838834764831845f);
    }
  }
  __syncthreads();

  // phase 4: S = e @ x_pad  (16 x 84)
  int cq = t & 31, rg = t >> 5;               // c = cq*4..+3 (cq<21), r = rg*2+{0,1}
  if (cq < 21) {
    float acc[2][4] = {{0,0,0,0},{0,0,0,0}};
    const float* xb_ = ws + OFF_XPAD + bb*LL*CP;
    for (int l4 = 0; l4 < 64; l4++) {
      float4 e0 = *(const float4*)&se[(rg*2+0)*260 + l4*4];
      float4 e1 = *(const float4*)&se[(rg*2+1)*260 + l4*4];
      float ev[2][4] = {{e0.x,e0.y,e0.z,e0.w},{e1.x,e1.y,e1.z,e1.w}};
      #pragma unroll
      for (int v = 0; v < 4; v++) {
        float4 x4 = *(const float4*)&xb_[(l4*4+v)*CP + cq*4];
        float xv[4] = {x4.x,x4.y,x4.z,x4.w};
        #pragma unroll
        for (int ri = 0; ri < 2; ri++)
          #pragma unroll
          for (int cu = 0; cu < 4; cu++)
            acc[ri][cu] = fmaf(ev[ri][v], xv[cu], acc[ri][cu]);
      }
    }
    for (int ri = 0; ri < 2; ri++) {
      float4 o4 = {acc[ri][0],acc[ri][1],acc[ri][2],acc[ri][3]};
      *(float4*)&sS[(rg*2+ri)*CP + cq*4] = o4;
    }
  }
  __syncthreads();

  // att transform: c<41: S[c]/S[41+c] (reads only cols>=41, writes only <41)
  for (int idx = t; idx < 16*41; idx += 256) {
    int rr = idx / 41, c = idx % 41;
    sS[rr*CP + c] = sS[rr*CP + c] / sS[rr*CP + 41 + c];
  }
  __syncthreads();
  // cols 41..82 = 1 (mask channels are exactly 1; 82 = bias augmentation), 83 = 0
  for (int idx = t; idx < 16*43; idx += 256) {
    int rr = idx / 43, c = 41 + idx % 43;
    sS[rr*CP + c] = (c < 83) ? 1.f : 0.f;
  }
  __syncthreads();
  // write att tile
  int base = OFF_ATT + (bb*LQn + qt*16)*CP;
  for (int idx = t; idx < 16*CP; idx += 256) ws[base + idx] = sS[idx];
}

// ---------------- K3: xproj = att @ WcT (fused Wo+w_ih, bias via aug col) ----------------
// 384 blocks = 64 row-tiles x 6 j-tiles, 256 thr
__global__ __launch_bounds__(256) void k3_xproj(float* ws) {
  __shared__ float at[64*CP];
  int mblk = blockIdx.x / 6, jblk = blockIdx.x % 6;
  int t = threadIdx.x;
  for (int ii = 0; ii < 21; ii++) {
    int idx = t + ii*256;
    at[idx] = ws[OFF_ATT + mblk*64*CP + idx];
  }
  __syncthreads();
  int j4l = t & 31, rg = t >> 5;
  float acc[8][4] = {};
  const float* wct = ws + OFF_WCT;
  int jg = jblk*128 + j4l*4;
  for (int c4 = 0; c4 < 21; c4++) {
    float wv[4][4];
    #pragma unroll
    for (int u = 0; u < 4; u++) {
      float4 w4 = *(const float4*)&wct[(c4*4+u)*768 + jg];
      wv[u][0]=w4.x; wv[u][1]=w4.y; wv[u][2]=w4.z; wv[u][3]=w4.w;
    }
    #pragma unroll
    for (int ri = 0; ri < 8; ri++) {
      float4 a4 = *(const float4*)&at[(rg*8+ri)*CP + c4*4];
      float av[4] = {a4.x,a4.y,a4.z,a4.w};
      #pragma unroll
      for (int u = 0; u < 4; u++)
        #pragma unroll
        for (int jj = 0; jj < 4; jj++)
          acc[ri][jj] = fmaf(av[u], wv[u][jj], acc[ri][jj]);
    }
  }
  float* dst = ws + (jblk < 3 ? OFF_XF : OFF_XB);
  int col = (jblk % 3)*128 + j4l*4;
  for (int ri = 0; ri < 8; ri++) {
    int row = mblk*64 + rg*8 + ri;
    float4 o4 = {acc[ri][0],acc[ri][1],acc[ri][2],acc[ri][3]};
    *(float4*)&dst[row*TNH + col] = o4;
  }
}

// ---------------- K4: bidirectional GRU ----------------
// 64 blocks = (b, dir), 384 thr; Whh fp16 in registers, h broadcast via readlane + fdot2
__global__ __launch_bounds__(384) void k4_gru(
    const float* __restrict__ bhhf, const float* __restrict__ bhhb,
    float* ws) {
  __shared__ float gh[TNH];
  __shared__ float hbuf[NH];
  int bb = blockIdx.x >> 1, dir = blockIdx.x & 1;
  int t = threadIdx.x, lane = t & 63;
  const unsigned int* w2g = (const unsigned int*)ws + OFF_WHH2 + dir*64*TNH;
  unsigned int w2[64];
  #pragma unroll
  for (int k2 = 0; k2 < 64; k2++) w2[k2] = w2g[k2*TNH + t];
  const float* bhh = dir ? bhhb : bhhf;
  const float* xp = ws + (dir ? OFF_XB : OFF_XF) + bb*LQn*TNH;
  float* hc = ws + OFF_HCAT + bb*LQn*2*NH + dir*NH;
  float b_r=0.f, b_z=0.f, b_n=0.f, hprev=0.f;
  if (t < NH) { b_r = bhh[t]; b_z = bhh[NH+t]; b_n = bhh[2*NH+t]; }
  unsigned int h2own = 0;

  for (int step = 0; step < LQn; step++) {
    int ti = dir ? (LQn-1-step) : step;
    float xr=0.f, xz=0.f, xn=0.f;
    if (t < NH) {
      xr = xp[ti*TNH + t];
      xz = xp[ti*TNH + NH + t];
      xn = xp[ti*TNH + 2*NH + t];
    }
    float a0 = 0.f, a1 = 0.f;
    #pragma unroll
    for (int k2 = 0; k2 < 64; k2++) {
      unsigned int hv = (unsigned int)__builtin_amdgcn_readlane((int)h2own, k2);
      h2_t hh = __builtin_bit_cast(h2_t, hv);
      h2_t wwv = __builtin_bit_cast(h2_t, w2[k2]);
      if (k2 & 1) a1 = __builtin_amdgcn_fdot2(hh, wwv, a1, false);
      else        a0 = __builtin_amdgcn_fdot2(hh, wwv, a0, false);
    }
    gh[t] = a0 + a1;
    __syncthreads();
    if (t < NH) {
      float r = 1.f/(1.f + __expf(-(xr + gh[t] + b_r)));
      float z = 1.f/(1.f + __expf(-(xz + gh[NH+t] + b_z)));
      float n = tanhf(xn + r*(gh[2*NH+t] + b_n));
      float hn = (1.f - z)*n + z*hprev;
      hprev = hn;
      hbuf[t] = hn;
      hc[ti*2*NH + t] = hn;
    }
    __syncthreads();
    float2 hp = *(const float2*)&hbuf[2*lane];
    union { _Float16 h[2]; unsigned int u; } pk;
    pk.h[0] = (_Float16)hp.x; pk.h[1] = (_Float16)hp.y;
    h2own = pk.u;
  }
}

// ---------------- K5: final MLP ----------------
// 128 blocks x 32 rows, 256 thr
__global__ __launch_bounds__(256) void k5_mlp(
    const float* __restrict__ W1, const float* __restrict__ b1,
    const float* __restrict__ W2, const float* __restrict__ b2,
    const float* __restrict__ ws, float* __restrict__ out) {
  __shared__ float hl[32*264];
  __shared__ float hid[32*52];
  int t = threadIdx.x;
  int rowbase = blockIdx.x * 32;
  for (int ii = 0; ii < 32; ii++) {
    int idx = t + ii*256;
    int r = idx >> 8, c = idx & 255;
    hl[r*264 + c] = ws[OFF_HCAT + (rowbase + r)*256 + c];
  }
  __syncthreads();
  int r = t & 31, mg = t >> 5;
  float acc[7];
  #pragma unroll
  for (int im = 0; im < 7; im++) {
    int m = mg + 8*im;
    acc[im] = (m < 50) ? b1[m] : 0.f;
  }
  for (int k4 = 0; k4 < 64; k4++) {
    float4 h4 = *(const float4*)&hl[r*264 + k4*4];
    #pragma unroll
    for (int im = 0; im < 7; im++) {
      int m = mg + 8*im;
      if (m < 50) {
        float4 w4 = *(const float4*)&W1[m*256 + k4*4];
        acc[im] = fmaf(h4.x, w4.x, acc[im]);
        acc[im] = fmaf(h4.y, w4.y, acc[im]);
        acc[im] = fmaf(h4.z, w4.z, acc[im]);
        acc[im] = fmaf(h4.w, w4.w, acc[im]);
      }
    }
  }
  #pragma unroll
  for (int im = 0; im < 7; im++) {
    int m = mg + 8*im;
    if (m < 50) hid[r*52 + m] = fmaxf(acc[im], 0.f);
  }
  __syncthreads();
  int og = mg;
  float a4[4];
  #pragma unroll
  for (int u = 0; u < 4; u++) a4[u] = b2[og*4 + u];
  for (int m = 0; m < 50; m++) {
    float hv = hid[r*52 + m];
    #pragma unroll
    for (int u = 0; u < 4; u++)
      a4[u] = fmaf(hv, W2[(og*4+u)*50 + m], a4[u]);
  }
  float4 o4 = {a4[0], a4[1], a4[2], a4[3]};
  *(float4*)&out[(rowbase + r)*32 + og*4] = o4;
}

extern "C" void kernel_launch(void* const* d_in, const int* in_sizes, int n_in,
                              void* d_out, int out_size, void* d_ws, size_t ws_size,
                              hipStream_t stream) {
  (void)in_sizes; (void)n_in; (void)out_size; (void)ws_size;
  const float* x      = (const float*)d_in[0];
  const float* tsteps = (const float*)d_in[1];
  const float* query  = (const float*)d_in[2];
  const float* Wq     = (const float*)d_in[3];
  const float* bq     = (const float*)d_in[4];
  const float* Wk     = (const float*)d_in[5];
  const float* bk     = (const float*)d_in[6];
  const float* Wo     = (const float*)d_in[7];
  const float* bo     = (const float*)d_in[8];
  const float* wihf   = (const float*)d_in[9];
  const float* whhf   = (const float*)d_in[10];
  const float* bihf   = (const float*)d_in[11];
  const float* bhhf   = (const float*)d_in[12];
  const float* wihb   = (const float*)d_in[13];
  const float* whhb   = (const float*)d_in[14];
  const float* bihb   = (const float*)d_in[15];
  const float* bhhb   = (const float*)d_in[16];
  const float* W1     = (const float*)d_in[17];
  const float* b1     = (const float*)d_in[18];
  const float* W2     = (const float*)d_in[19];
  const float* b2     = (const float*)d_in[20];
  float* ws = (float*)d_ws;

  k0_prep<<<3260, 256, 0, stream>>>(x, Wq, Wk, Wo, bo, wihf, bihf, wihb, bihb, whhf, whhb, ws);
  k1_embed_proj<<<192, 256, 0, stream>>>(query, tsteps, bq, bk, ws);
  k2_attn<<<256, 256, 0, stream>>>(ws);
  k3_xproj<<<384, 256, 0, stream>>>(ws);
  k4_gru<<<64, 384, 0, stream>>>(bhhf, bhhb, ws);
  k5_mlp<<<128, 256, 0, stream>>>(W1, b1, W2, b2, ws, (float*)d_out);
}